// Round 1
// baseline (1486.499 us; speedup 1.0000x reference)
//
#include <hip/hip_runtime.h>

#define IN_DIM 128
#define OUT_DIM 128
#define BM 64      // nodes per block (GEMM)
#define KT 32      // k-tile

// ---------------------------------------------------------------------------
// K2: A[dst[e]] += X[src[e]]  (32 threads per edge, float4 per thread,
// 4x global_atomic_add_f32 each). X rows are 512B; a wave covers 2 edges
// with fully coalesced 16B/lane reads.
// ---------------------------------------------------------------------------
__global__ void scatter_kernel(const float* __restrict__ X,
                               const int* __restrict__ src,
                               const int* __restrict__ dst,
                               float* __restrict__ A,
                               int n_edges) {
    int gtid = blockIdx.x * blockDim.x + threadIdx.x;
    int e = gtid >> 5;   // edge index
    if (e >= n_edges) return;
    int sub = gtid & 31; // which float4 chunk of the 128-dim row

    int s = src[e];      // 32 lanes same addr -> single line + broadcast
    int d = dst[e];

    const float4 v = *reinterpret_cast<const float4*>(
        X + (size_t)s * IN_DIM + sub * 4);
    float* o = A + (size_t)d * IN_DIM + sub * 4;
    unsafeAtomicAdd(o + 0, v.x);
    unsafeAtomicAdd(o + 1, v.y);
    unsafeAtomicAdd(o + 2, v.z);
    unsafeAtomicAdd(o + 3, v.w);
}

// ---------------------------------------------------------------------------
// K3: out[n] = relu(Wself @ X[n] + Wneigh @ A[n] + bias)
// Block: 256 threads = 64 nodes x 128 outs. Thread tile: 8 nodes x 4 outs.
// LDS: Wt[k][o] transposed tile (stride 132 -> full-bank b128 reads),
//      Xs[node][k] (stride 36 -> broadcast/2-way reads, free).
// k runs over 256 = [X | A] concatenation; W switches at k=128.
// ---------------------------------------------------------------------------
__global__ __launch_bounds__(256)
void gemm_kernel(const float* __restrict__ X,
                 const float* __restrict__ A,
                 const float* __restrict__ Wself,   // [out][in]
                 const float* __restrict__ Wneigh,  // [out][in]
                 const float* __restrict__ bias,
                 float* __restrict__ out,
                 int n_nodes) {
    __shared__ alignas(16) float Wt[KT][132];      // [k][o], padded
    __shared__ alignas(16) float Xs[BM][KT + 4];   // [node][k], stride 36

    const int tid   = threadIdx.x;
    const int o_grp = tid & 31;   // 32 groups -> 4 outs each
    const int n_grp = tid >> 5;   // 8 groups  -> 8 nodes each
    const int node0 = blockIdx.x * BM;

    float acc[8][4];
    #pragma unroll
    for (int i = 0; i < 8; ++i)
        #pragma unroll
        for (int j = 0; j < 4; ++j) acc[i][j] = 0.f;

    for (int kt = 0; kt < 2 * IN_DIM; kt += KT) {
        const float* Wsrc = (kt < IN_DIM) ? Wself : Wneigh;
        const float* Fsrc = (kt < IN_DIM) ? X : A;
        const int kbase = kt & (IN_DIM - 1);

        __syncthreads();   // protect LDS from previous iter's readers

        // ---- stage Wt[k][o] <- Wsrc[o][kbase+k], float4 along k ----
        {
            const int k4 = tid & 7;        // 0..7 -> k = 4*k4..4*k4+3
            int o = tid >> 3;              // 0..31, +32 per pass
            #pragma unroll
            for (int p = 0; p < 4; ++p, o += 32) {
                float4 w = *reinterpret_cast<const float4*>(
                    Wsrc + o * IN_DIM + kbase + k4 * 4);
                Wt[k4 * 4 + 0][o] = w.x;
                Wt[k4 * 4 + 1][o] = w.y;
                Wt[k4 * 4 + 2][o] = w.z;
                Wt[k4 * 4 + 3][o] = w.w;
            }
        }
        // ---- stage Xs[n][k] <- Fsrc[node0+n][kbase+k] ----
        {
            const int k4 = tid & 7;
            int n = tid >> 3;
            #pragma unroll
            for (int p = 0; p < 2; ++p, n += 32) {
                const int node = node0 + n;
                float4 x = make_float4(0.f, 0.f, 0.f, 0.f);
                if (node < n_nodes)
                    x = *reinterpret_cast<const float4*>(
                        Fsrc + (size_t)node * IN_DIM + kbase + k4 * 4);
                *reinterpret_cast<float4*>(&Xs[n][k4 * 4]) = x;
            }
        }
        __syncthreads();

        // ---- compute: acc[nn][oo] += x[k] * Wt[k][o] ----
        #pragma unroll
        for (int k4 = 0; k4 < KT; k4 += 4) {
            float4 w0 = *reinterpret_cast<const float4*>(&Wt[k4 + 0][o_grp * 4]);
            float4 w1 = *reinterpret_cast<const float4*>(&Wt[k4 + 1][o_grp * 4]);
            float4 w2 = *reinterpret_cast<const float4*>(&Wt[k4 + 2][o_grp * 4]);
            float4 w3 = *reinterpret_cast<const float4*>(&Wt[k4 + 3][o_grp * 4]);
            #pragma unroll
            for (int nn = 0; nn < 8; ++nn) {
                float4 x = *reinterpret_cast<const float4*>(
                    &Xs[n_grp * 8 + nn][k4]);
                acc[nn][0] = fmaf(x.x, w0.x, acc[nn][0]);
                acc[nn][0] = fmaf(x.y, w1.x, acc[nn][0]);
                acc[nn][0] = fmaf(x.z, w2.x, acc[nn][0]);
                acc[nn][0] = fmaf(x.w, w3.x, acc[nn][0]);
                acc[nn][1] = fmaf(x.x, w0.y, acc[nn][1]);
                acc[nn][1] = fmaf(x.y, w1.y, acc[nn][1]);
                acc[nn][1] = fmaf(x.z, w2.y, acc[nn][1]);
                acc[nn][1] = fmaf(x.w, w3.y, acc[nn][1]);
                acc[nn][2] = fmaf(x.x, w0.z, acc[nn][2]);
                acc[nn][2] = fmaf(x.y, w1.z, acc[nn][2]);
                acc[nn][2] = fmaf(x.z, w2.z, acc[nn][2]);
                acc[nn][2] = fmaf(x.w, w3.z, acc[nn][2]);
                acc[nn][3] = fmaf(x.x, w0.w, acc[nn][3]);
                acc[nn][3] = fmaf(x.y, w1.w, acc[nn][3]);
                acc[nn][3] = fmaf(x.z, w2.w, acc[nn][3]);
                acc[nn][3] = fmaf(x.w, w3.w, acc[nn][3]);
            }
        }
    }

    // ---- epilogue: bias + relu + coalesced float4 store ----
    const float4 b = *reinterpret_cast<const float4*>(bias + o_grp * 4);
    #pragma unroll
    for (int nn = 0; nn < 8; ++nn) {
        const int node = node0 + n_grp * 8 + nn;
        if (node < n_nodes) {
            float4 r;
            r.x = fmaxf(acc[nn][0] + b.x, 0.f);
            r.y = fmaxf(acc[nn][1] + b.y, 0.f);
            r.z = fmaxf(acc[nn][2] + b.z, 0.f);
            r.w = fmaxf(acc[nn][3] + b.w, 0.f);
            *reinterpret_cast<float4*>(
                out + (size_t)node * OUT_DIM + o_grp * 4) = r;
        }
    }
}

// ---------------------------------------------------------------------------
extern "C" void kernel_launch(void* const* d_in, const int* in_sizes, int n_in,
                              void* d_out, int out_size, void* d_ws, size_t ws_size,
                              hipStream_t stream) {
    const float* X      = (const float*)d_in[0];
    const int*   src    = (const int*)d_in[1];
    const int*   dst    = (const int*)d_in[2];
    const float* Wself  = (const float*)d_in[3];
    const float* Wneigh = (const float*)d_in[4];
    const float* bias   = (const float*)d_in[5];
    float*       out    = (float*)d_out;

    const int n_nodes = in_sizes[0] / IN_DIM;
    const int n_edges = in_sizes[1];

    float* A = (float*)d_ws;  // [n_nodes][128] accumulator
    const size_t abytes = (size_t)n_nodes * IN_DIM * sizeof(float);
    hipMemsetAsync(A, 0, abytes, stream);

    const long long sthreads = (long long)n_edges * 32;
    const int sblocks = (int)((sthreads + 255) / 256);
    scatter_kernel<<<sblocks, 256, 0, stream>>>(X, src, dst, A, n_edges);

    const int gblocks = (n_nodes + BM - 1) / BM;
    gemm_kernel<<<gblocks, 256, 0, stream>>>(X, A, Wself, Wneigh, bias, out,
                                             n_nodes);
}

// Round 2
// 296.025 us; speedup vs baseline: 5.0215x; 5.0215x over previous
//
#include <hip/hip_runtime.h>

#define IN_DIM 128
#define OUT_DIM 128
#define BM 64      // nodes per block (GEMM)
#define KT 32      // k-tile

// ===========================================================================
// Fallback path (R1): f32 atomics — only used if ws_size is too small.
// ===========================================================================
__global__ void scatter_kernel(const float* __restrict__ X,
                               const int* __restrict__ src,
                               const int* __restrict__ dst,
                               float* __restrict__ A,
                               int n_edges) {
    int gtid = blockIdx.x * blockDim.x + threadIdx.x;
    int e = gtid >> 5;
    if (e >= n_edges) return;
    int sub = gtid & 31;
    int s = src[e];
    int d = dst[e];
    const float4 v = *reinterpret_cast<const float4*>(
        X + (size_t)s * IN_DIM + sub * 4);
    float* o = A + (size_t)d * IN_DIM + sub * 4;
    unsafeAtomicAdd(o + 0, v.x);
    unsafeAtomicAdd(o + 1, v.y);
    unsafeAtomicAdd(o + 2, v.z);
    unsafeAtomicAdd(o + 3, v.w);
}

// ===========================================================================
// CSR binning path
// ===========================================================================
__global__ void hist_kernel(const int* __restrict__ dst, int* __restrict__ counts,
                            int n_edges) {
    int e = blockIdx.x * blockDim.x + threadIdx.x;
    if (e < n_edges) atomicAdd(&counts[dst[e]], 1);
}

// Per-block (256-wide) scan: offs[i] = exclusive scan of counts within block,
// bsums[b] = block total.
__global__ __launch_bounds__(256)
void scan1_kernel(const int* __restrict__ counts, int* __restrict__ offs,
                  int* __restrict__ bsums, int n) {
    __shared__ int tmp[256];
    const int tid = threadIdx.x;
    const int i = blockIdx.x * 256 + tid;
    const int v = (i < n) ? counts[i] : 0;
    tmp[tid] = v;
    __syncthreads();
    #pragma unroll
    for (int d = 1; d < 256; d <<= 1) {
        int t = (tid >= d) ? tmp[tid - d] : 0;
        __syncthreads();
        tmp[tid] += t;
        __syncthreads();
    }
    if (i < n) offs[i] = tmp[tid] - v;            // exclusive
    if (tid == 255) bsums[blockIdx.x] = tmp[255]; // block total
}

// Single-block exclusive scan of block sums (handles nb > 256 via carry loop).
__global__ __launch_bounds__(256)
void scan2_kernel(int* __restrict__ bsums, int nb) {
    __shared__ int tmp[256];
    __shared__ int carry;
    const int tid = threadIdx.x;
    if (tid == 0) carry = 0;
    __syncthreads();
    for (int base = 0; base < nb; base += 256) {
        const int i = base + tid;
        const int v = (i < nb) ? bsums[i] : 0;
        tmp[tid] = v;
        __syncthreads();
        #pragma unroll
        for (int d = 1; d < 256; d <<= 1) {
            int t = (tid >= d) ? tmp[tid - d] : 0;
            __syncthreads();
            tmp[tid] += t;
            __syncthreads();
        }
        if (i < nb) bsums[i] = carry + tmp[tid] - v;  // exclusive + carry
        __syncthreads();
        if (tid == 0) carry += tmp[255];
        __syncthreads();
    }
}

// offs += block offset; cursor = offs (bucket write pointers).
__global__ __launch_bounds__(256)
void scan3_kernel(int* __restrict__ offs, const int* __restrict__ bsums,
                  int* __restrict__ cursor, int n) {
    const int i = blockIdx.x * 256 + threadIdx.x;
    if (i < n) {
        const int o = offs[i] + bsums[blockIdx.x];
        offs[i] = o;
        cursor[i] = o;
    }
}

// src_sorted[pos] = src[e], pos grabbed per-destination.
__global__ void bucket_kernel(const int* __restrict__ src,
                              const int* __restrict__ dst,
                              int* __restrict__ cursor,
                              int* __restrict__ src_sorted, int n_edges) {
    int e = blockIdx.x * blockDim.x + threadIdx.x;
    if (e < n_edges) {
        const int pos = atomicAdd(&cursor[dst[e]], 1);
        src_sorted[pos] = src[e];
    }
}

// A[u] = sum over incoming edges of X[src]. 32 lanes per node, float4/lane,
// conflict-free register accumulation, one coalesced row write.
__global__ __launch_bounds__(256)
void accum_kernel(const float* __restrict__ X,
                  const int* __restrict__ offs,
                  const int* __restrict__ src_sorted,
                  float* __restrict__ A, int n_nodes, int n_edges) {
    const int tid = threadIdx.x;
    const int u = blockIdx.x * 8 + (tid >> 5);
    if (u >= n_nodes) return;
    const int sub = tid & 31;

    const int beg = offs[u];
    const int end = (u == n_nodes - 1) ? n_edges : offs[u + 1];

    float4 acc = make_float4(0.f, 0.f, 0.f, 0.f);
    for (int e = beg; e < end; ++e) {
        const int s = src_sorted[e];  // broadcast across the 32-lane group
        const float4 v = *reinterpret_cast<const float4*>(
            X + (size_t)s * IN_DIM + sub * 4);
        acc.x += v.x; acc.y += v.y; acc.z += v.z; acc.w += v.w;
    }
    *reinterpret_cast<float4*>(A + (size_t)u * IN_DIM + sub * 4) = acc;
}

// ===========================================================================
// K3: out[n] = relu(Wself @ X[n] + Wneigh @ A[n] + bias)   (unchanged R1)
// ===========================================================================
__global__ __launch_bounds__(256)
void gemm_kernel(const float* __restrict__ X,
                 const float* __restrict__ A,
                 const float* __restrict__ Wself,   // [out][in]
                 const float* __restrict__ Wneigh,  // [out][in]
                 const float* __restrict__ bias,
                 float* __restrict__ out,
                 int n_nodes) {
    __shared__ alignas(16) float Wt[KT][132];      // [k][o], padded
    __shared__ alignas(16) float Xs[BM][KT + 4];   // [node][k], stride 36

    const int tid   = threadIdx.x;
    const int o_grp = tid & 31;
    const int n_grp = tid >> 5;
    const int node0 = blockIdx.x * BM;

    float acc[8][4];
    #pragma unroll
    for (int i = 0; i < 8; ++i)
        #pragma unroll
        for (int j = 0; j < 4; ++j) acc[i][j] = 0.f;

    for (int kt = 0; kt < 2 * IN_DIM; kt += KT) {
        const float* Wsrc = (kt < IN_DIM) ? Wself : Wneigh;
        const float* Fsrc = (kt < IN_DIM) ? X : A;
        const int kbase = kt & (IN_DIM - 1);

        __syncthreads();

        {
            const int k4 = tid & 7;
            int o = tid >> 3;
            #pragma unroll
            for (int p = 0; p < 4; ++p, o += 32) {
                float4 w = *reinterpret_cast<const float4*>(
                    Wsrc + o * IN_DIM + kbase + k4 * 4);
                Wt[k4 * 4 + 0][o] = w.x;
                Wt[k4 * 4 + 1][o] = w.y;
                Wt[k4 * 4 + 2][o] = w.z;
                Wt[k4 * 4 + 3][o] = w.w;
            }
        }
        {
            const int k4 = tid & 7;
            int n = tid >> 3;
            #pragma unroll
            for (int p = 0; p < 2; ++p, n += 32) {
                const int node = node0 + n;
                float4 x = make_float4(0.f, 0.f, 0.f, 0.f);
                if (node < n_nodes)
                    x = *reinterpret_cast<const float4*>(
                        Fsrc + (size_t)node * IN_DIM + kbase + k4 * 4);
                *reinterpret_cast<float4*>(&Xs[n][k4 * 4]) = x;
            }
        }
        __syncthreads();

        #pragma unroll
        for (int k4 = 0; k4 < KT; k4 += 4) {
            float4 w0 = *reinterpret_cast<const float4*>(&Wt[k4 + 0][o_grp * 4]);
            float4 w1 = *reinterpret_cast<const float4*>(&Wt[k4 + 1][o_grp * 4]);
            float4 w2 = *reinterpret_cast<const float4*>(&Wt[k4 + 2][o_grp * 4]);
            float4 w3 = *reinterpret_cast<const float4*>(&Wt[k4 + 3][o_grp * 4]);
            #pragma unroll
            for (int nn = 0; nn < 8; ++nn) {
                float4 x = *reinterpret_cast<const float4*>(
                    &Xs[n_grp * 8 + nn][k4]);
                acc[nn][0] = fmaf(x.x, w0.x, acc[nn][0]);
                acc[nn][0] = fmaf(x.y, w1.x, acc[nn][0]);
                acc[nn][0] = fmaf(x.z, w2.x, acc[nn][0]);
                acc[nn][0] = fmaf(x.w, w3.x, acc[nn][0]);
                acc[nn][1] = fmaf(x.x, w0.y, acc[nn][1]);
                acc[nn][1] = fmaf(x.y, w1.y, acc[nn][1]);
                acc[nn][1] = fmaf(x.z, w2.y, acc[nn][1]);
                acc[nn][1] = fmaf(x.w, w3.y, acc[nn][1]);
                acc[nn][2] = fmaf(x.x, w0.z, acc[nn][2]);
                acc[nn][2] = fmaf(x.y, w1.z, acc[nn][2]);
                acc[nn][2] = fmaf(x.z, w2.z, acc[nn][2]);
                acc[nn][2] = fmaf(x.w, w3.z, acc[nn][2]);
                acc[nn][3] = fmaf(x.x, w0.w, acc[nn][3]);
                acc[nn][3] = fmaf(x.y, w1.w, acc[nn][3]);
                acc[nn][3] = fmaf(x.z, w2.w, acc[nn][3]);
                acc[nn][3] = fmaf(x.w, w3.w, acc[nn][3]);
            }
        }
    }

    const float4 b = *reinterpret_cast<const float4*>(bias + o_grp * 4);
    #pragma unroll
    for (int nn = 0; nn < 8; ++nn) {
        const int node = node0 + n_grp * 8 + nn;
        if (node < n_nodes) {
            float4 r;
            r.x = fmaxf(acc[nn][0] + b.x, 0.f);
            r.y = fmaxf(acc[nn][1] + b.y, 0.f);
            r.z = fmaxf(acc[nn][2] + b.z, 0.f);
            r.w = fmaxf(acc[nn][3] + b.w, 0.f);
            *reinterpret_cast<float4*>(
                out + (size_t)node * OUT_DIM + o_grp * 4) = r;
        }
    }
}

// ===========================================================================
extern "C" void kernel_launch(void* const* d_in, const int* in_sizes, int n_in,
                              void* d_out, int out_size, void* d_ws, size_t ws_size,
                              hipStream_t stream) {
    const float* X      = (const float*)d_in[0];
    const int*   src    = (const int*)d_in[1];
    const int*   dst    = (const int*)d_in[2];
    const float* Wself  = (const float*)d_in[3];
    const float* Wneigh = (const float*)d_in[4];
    const float* bias   = (const float*)d_in[5];
    float*       out    = (float*)d_out;

    const int n_nodes = in_sizes[0] / IN_DIM;
    const int n_edges = in_sizes[1];
    const int nb = (n_nodes + 255) / 256;   // scan blocks

    // --- workspace layout (16B aligned slices) ---
    char* w = (char*)d_ws;
    auto take = [&](size_t bytes) {
        char* p = w;
        w += (bytes + 15) & ~(size_t)15;
        return p;
    };
    float* A         = (float*)take((size_t)n_nodes * IN_DIM * sizeof(float));
    int*   counts    = (int*)take((size_t)n_nodes * sizeof(int));
    int*   offs      = (int*)take((size_t)n_nodes * sizeof(int));
    int*   cursor    = (int*)take((size_t)n_nodes * sizeof(int));
    int*   bsums     = (int*)take((size_t)nb * sizeof(int));
    int*   srcsorted = (int*)take((size_t)n_edges * sizeof(int));
    const size_t needed = (size_t)(w - (char*)d_ws);

    const int eblocks = (n_edges + 255) / 256;

    if (needed <= ws_size) {
        // ---- CSR binning path ----
        hipMemsetAsync(counts, 0, (size_t)n_nodes * sizeof(int), stream);
        hist_kernel<<<eblocks, 256, 0, stream>>>(dst, counts, n_edges);
        scan1_kernel<<<nb, 256, 0, stream>>>(counts, offs, bsums, n_nodes);
        scan2_kernel<<<1, 256, 0, stream>>>(bsums, nb);
        scan3_kernel<<<nb, 256, 0, stream>>>(offs, bsums, cursor, n_nodes);
        bucket_kernel<<<eblocks, 256, 0, stream>>>(src, dst, cursor, srcsorted,
                                                   n_edges);
        accum_kernel<<<(n_nodes + 7) / 8, 256, 0, stream>>>(
            X, offs, srcsorted, A, n_nodes, n_edges);
    } else {
        // ---- fallback: f32 atomic scatter ----
        hipMemsetAsync(A, 0, (size_t)n_nodes * IN_DIM * sizeof(float), stream);
        const long long sthreads = (long long)n_edges * 32;
        const int sblocks = (int)((sthreads + 255) / 256);
        scatter_kernel<<<sblocks, 256, 0, stream>>>(X, src, dst, A, n_edges);
    }

    const int gblocks = (n_nodes + BM - 1) / BM;
    gemm_kernel<<<gblocks, 256, 0, stream>>>(X, A, Wself, Wneigh, bias, out,
                                             n_nodes);
}

// Round 3
// 264.450 us; speedup vs baseline: 5.6211x; 1.1194x over previous
//
#include <hip/hip_runtime.h>

#define IN_DIM 128
#define OUT_DIM 128
#define BM 64      // nodes per block (f32 fallback GEMM)
#define KT 32      // k-tile (f32 fallback GEMM)

typedef __attribute__((ext_vector_type(8))) short short8v;   // 8 bf16 (4 VGPR)
typedef __attribute__((ext_vector_type(4))) float float4v;   // 4 fp32 acc

// ---- bf16 split helpers ----------------------------------------------------
__device__ __forceinline__ unsigned short bf16_hi(float x) {
    unsigned int u = __float_as_uint(x);
    return (unsigned short)((u + 0x7fffu + ((u >> 16) & 1u)) >> 16);
}
__device__ __forceinline__ float bf16_tof(unsigned short h) {
    return __uint_as_float(((unsigned int)h) << 16);
}

// ===========================================================================
// Fallback path (R1): f32 atomics — only used if ws_size is too small.
// ===========================================================================
__global__ void scatter_kernel(const float* __restrict__ X,
                               const int* __restrict__ src,
                               const int* __restrict__ dst,
                               float* __restrict__ A,
                               int n_edges) {
    int gtid = blockIdx.x * blockDim.x + threadIdx.x;
    int e = gtid >> 5;
    if (e >= n_edges) return;
    int sub = gtid & 31;
    int s = src[e];
    int d = dst[e];
    const float4 v = *reinterpret_cast<const float4*>(
        X + (size_t)s * IN_DIM + sub * 4);
    float* o = A + (size_t)d * IN_DIM + sub * 4;
    unsafeAtomicAdd(o + 0, v.x);
    unsafeAtomicAdd(o + 1, v.y);
    unsafeAtomicAdd(o + 2, v.z);
    unsafeAtomicAdd(o + 3, v.w);
}

// ===========================================================================
// CSR binning
// ===========================================================================
__global__ void hist_kernel(const int* __restrict__ dst, int* __restrict__ counts,
                            int n_edges) {
    int i = blockIdx.x * blockDim.x + threadIdx.x;   // 1 thread = 4 edges
    int e0 = i * 4;
    if (e0 + 4 <= n_edges) {
        int4 d4 = *reinterpret_cast<const int4*>(dst + e0);
        atomicAdd(&counts[d4.x], 1);
        atomicAdd(&counts[d4.y], 1);
        atomicAdd(&counts[d4.z], 1);
        atomicAdd(&counts[d4.w], 1);
    } else {
        for (int e = e0; e < n_edges; ++e) atomicAdd(&counts[dst[e]], 1);
    }
}

__global__ __launch_bounds__(256)
void scan1_kernel(const int* __restrict__ counts, int* __restrict__ offs,
                  int* __restrict__ bsums, int n) {
    __shared__ int tmp[256];
    const int tid = threadIdx.x;
    const int i = blockIdx.x * 256 + tid;
    const int v = (i < n) ? counts[i] : 0;
    tmp[tid] = v;
    __syncthreads();
    #pragma unroll
    for (int d = 1; d < 256; d <<= 1) {
        int t = (tid >= d) ? tmp[tid - d] : 0;
        __syncthreads();
        tmp[tid] += t;
        __syncthreads();
    }
    if (i < n) offs[i] = tmp[tid] - v;
    if (tid == 255) bsums[blockIdx.x] = tmp[255];
}

__global__ __launch_bounds__(256)
void scan2_kernel(int* __restrict__ bsums, int nb) {
    __shared__ int tmp[256];
    __shared__ int carry;
    const int tid = threadIdx.x;
    if (tid == 0) carry = 0;
    __syncthreads();
    for (int base = 0; base < nb; base += 256) {
        const int i = base + tid;
        const int v = (i < nb) ? bsums[i] : 0;
        tmp[tid] = v;
        __syncthreads();
        #pragma unroll
        for (int d = 1; d < 256; d <<= 1) {
            int t = (tid >= d) ? tmp[tid - d] : 0;
            __syncthreads();
            tmp[tid] += t;
            __syncthreads();
        }
        if (i < nb) bsums[i] = carry + tmp[tid] - v;
        __syncthreads();
        if (tid == 0) carry += tmp[255];
        __syncthreads();
    }
}

__global__ __launch_bounds__(256)
void scan3_kernel(int* __restrict__ offs, const int* __restrict__ bsums,
                  int* __restrict__ cursor, int n) {
    const int i = blockIdx.x * 256 + threadIdx.x;
    if (i < n) {
        const int o = offs[i] + bsums[blockIdx.x];
        offs[i] = o;
        cursor[i] = o;
    }
}

__global__ void bucket_kernel(const int* __restrict__ src,
                              const int* __restrict__ dst,
                              int* __restrict__ cursor,
                              int* __restrict__ src_sorted, int n_edges) {
    int e = blockIdx.x * blockDim.x + threadIdx.x;
    if (e < n_edges) {
        const int pos = atomicAdd(&cursor[dst[e]], 1);
        src_sorted[pos] = src[e];
    }
}

// A[u] = sum X[src] over incoming edges; emits bf16 hi/lo split.
// 32 lanes per node, float4/lane, 4-edge unroll for MLP.
__global__ __launch_bounds__(256)
void accum_split_kernel(const float* __restrict__ X,
                        const int* __restrict__ offs,
                        const int* __restrict__ src_sorted,
                        unsigned short* __restrict__ Ahi,
                        unsigned short* __restrict__ Alo,
                        int n_nodes, int n_edges) {
    const int tid = threadIdx.x;
    const int u = blockIdx.x * 8 + (tid >> 5);
    if (u >= n_nodes) return;
    const int sub = tid & 31;

    const int beg = offs[u];
    const int end = (u == n_nodes - 1) ? n_edges : offs[u + 1];

    float4 acc = make_float4(0.f, 0.f, 0.f, 0.f);
    int e = beg;
    for (; e + 4 <= end; e += 4) {
        const int s0 = src_sorted[e + 0];
        const int s1 = src_sorted[e + 1];
        const int s2 = src_sorted[e + 2];
        const int s3 = src_sorted[e + 3];
        const float4 v0 = *reinterpret_cast<const float4*>(X + (size_t)s0 * IN_DIM + sub * 4);
        const float4 v1 = *reinterpret_cast<const float4*>(X + (size_t)s1 * IN_DIM + sub * 4);
        const float4 v2 = *reinterpret_cast<const float4*>(X + (size_t)s2 * IN_DIM + sub * 4);
        const float4 v3 = *reinterpret_cast<const float4*>(X + (size_t)s3 * IN_DIM + sub * 4);
        acc.x += v0.x + v1.x + v2.x + v3.x;
        acc.y += v0.y + v1.y + v2.y + v3.y;
        acc.z += v0.z + v1.z + v2.z + v3.z;
        acc.w += v0.w + v1.w + v2.w + v3.w;
    }
    for (; e < end; ++e) {
        const int s = src_sorted[e];
        const float4 v = *reinterpret_cast<const float4*>(X + (size_t)s * IN_DIM + sub * 4);
        acc.x += v.x; acc.y += v.y; acc.z += v.z; acc.w += v.w;
    }

    ushort4 hi, lo;
    hi.x = bf16_hi(acc.x); lo.x = bf16_hi(acc.x - bf16_tof(hi.x));
    hi.y = bf16_hi(acc.y); lo.y = bf16_hi(acc.y - bf16_tof(hi.y));
    hi.z = bf16_hi(acc.z); lo.z = bf16_hi(acc.z - bf16_tof(hi.z));
    hi.w = bf16_hi(acc.w); lo.w = bf16_hi(acc.w - bf16_tof(hi.w));
    *reinterpret_cast<ushort4*>(Ahi + (size_t)u * IN_DIM + sub * 4) = hi;
    *reinterpret_cast<ushort4*>(Alo + (size_t)u * IN_DIM + sub * 4) = lo;
}

// ===========================================================================
// xsplit: X f32 -> per-node packed [hi[128] | lo[128]] bf16, stored in d_out.
// Node n's slot = d_out bytes [n*512, n*512+512) — exactly out row n, and the
// MFMA GEMM reads only its own block's rows before overwriting them.
// ===========================================================================
__global__ void xsplit_kernel(const float* __restrict__ X,
                              unsigned short* __restrict__ Xsp, int n_nodes) {
    int i = blockIdx.x * blockDim.x + threadIdx.x;   // n_nodes*32 float4 groups
    if (i >= n_nodes * 32) return;
    const int node = i >> 5, g = i & 31;
    const float4 x = *reinterpret_cast<const float4*>(X + (size_t)node * IN_DIM + g * 4);
    ushort4 hi, lo;
    hi.x = bf16_hi(x.x); lo.x = bf16_hi(x.x - bf16_tof(hi.x));
    hi.y = bf16_hi(x.y); lo.y = bf16_hi(x.y - bf16_tof(hi.y));
    hi.z = bf16_hi(x.z); lo.z = bf16_hi(x.z - bf16_tof(hi.z));
    hi.w = bf16_hi(x.w); lo.w = bf16_hi(x.w - bf16_tof(hi.w));
    *reinterpret_cast<ushort4*>(Xsp + (size_t)node * 256 + g * 4) = hi;
    *reinterpret_cast<ushort4*>(Xsp + (size_t)node * 256 + 128 + g * 4) = lo;
}

__global__ void wsplit_kernel(const float* __restrict__ W1,
                              const float* __restrict__ W2,
                              unsigned short* __restrict__ W1h,
                              unsigned short* __restrict__ W1l,
                              unsigned short* __restrict__ W2h,
                              unsigned short* __restrict__ W2l) {
    int i = blockIdx.x * blockDim.x + threadIdx.x;   // 16384
    if (i >= OUT_DIM * IN_DIM) return;
    float a = W1[i], b = W2[i];
    unsigned short ah = bf16_hi(a), bh = bf16_hi(b);
    W1h[i] = ah; W1l[i] = bf16_hi(a - bf16_tof(ah));
    W2h[i] = bh; W2l[i] = bf16_hi(b - bf16_tof(bh));
}

// ===========================================================================
// MFMA GEMM: out[n][o] = relu( sum over 6 bf16 K-segments + bias )
// segs: Xhi*W1h, Xhi*W1l, Xlo*W1h, Ahi*W2h, Ahi*W2l, Alo*W2h  (K=6*128=768)
// Tile: 64 nodes x 128 outs, 4 waves (2x2), wave tile 32x64, BK=64,
// mfma_f32_16x16x32_bf16. LDS: Fs 8KB + Ws 16KB, chunk-XOR swizzled (T2).
// Reg-staged with next-tile prefetch (T14-lite).
// ===========================================================================
__global__ __launch_bounds__(256, 4)
void mfma_gemm_kernel(const unsigned short* Xsp,          // aliases `out`!
                      const unsigned short* __restrict__ Ahi,
                      const unsigned short* __restrict__ Alo,
                      const unsigned short* __restrict__ W1h,
                      const unsigned short* __restrict__ W1l,
                      const unsigned short* __restrict__ W2h,
                      const unsigned short* __restrict__ W2l,
                      const float* __restrict__ bias,
                      float* out,
                      int n_nodes) {
    __shared__ unsigned short Fs[64 * 64];    // [node][k] swizzled, 8 KB
    __shared__ unsigned short Ws[128 * 64];   // [o][k]    swizzled, 16 KB

    const int tid  = threadIdx.x;
    const int lane = tid & 63;
    const int wid  = tid >> 6;
    const int wm   = wid >> 1;          // 0..1  (node half)
    const int wn   = wid & 1;           // 0..1  (out half)
    const int lr   = lane & 15;
    const int lk   = lane >> 4;         // 0..3
    const int node0 = blockIdx.x * 64;

    // staging geometry: chunk c of 8 bf16 (16 B); 8 chunks per 64-k row
    const int fr = tid >> 3;            // base row 0..31
    const int c  = tid & 7;             // chunk in row
    const int swz = (c ^ (fr & 7)) * 8; // LDS-side swizzled element offset

    float4v acc[2][4];
    #pragma unroll
    for (int mi = 0; mi < 2; ++mi)
        #pragma unroll
        for (int ni = 0; ni < 4; ++ni) acc[mi][ni] = (float4v)0.f;

    const unsigned short* wseg[6] = {W1h, W1l, W1h, W2h, W2l, W2h};

    short8v fv[2], wv[4];

    // ---- prologue: load tile 0 ----
    {
        const int seg = 0, khalf = 0;
        #pragma unroll
        for (int j = 0; j < 2; ++j) {
            const int node = node0 + fr + j * 32;
            short8v v = (short8v)0;
            if (node < n_nodes)
                v = *reinterpret_cast<const short8v*>(
                    Xsp + (size_t)node * 256 + khalf + c * 8);
            fv[j] = v;
        }
        #pragma unroll
        for (int j = 0; j < 4; ++j)
            wv[j] = *reinterpret_cast<const short8v*>(
                wseg[seg] + (size_t)(fr + j * 32) * 128 + khalf + c * 8);
    }

    #pragma unroll
    for (int t = 0; t < 12; ++t) {
        __syncthreads();   // protect LDS from previous tile's readers
        #pragma unroll
        for (int j = 0; j < 2; ++j)
            *reinterpret_cast<short8v*>(&Fs[(fr + j * 32) * 64 + swz]) = fv[j];
        #pragma unroll
        for (int j = 0; j < 4; ++j)
            *reinterpret_cast<short8v*>(&Ws[(fr + j * 32) * 64 + swz]) = wv[j];
        __syncthreads();

        // ---- prefetch tile t+1 (hides under MFMA phase) ----
        if (t < 11) {
            const int tn = t + 1;
            const int seg = tn >> 1;
            const int khalf = (tn & 1) * 64;
            #pragma unroll
            for (int j = 0; j < 2; ++j) {
                const int node = node0 + fr + j * 32;
                short8v v = (short8v)0;
                if (node < n_nodes) {
                    if (seg < 3) {
                        v = *reinterpret_cast<const short8v*>(
                            Xsp + (size_t)node * 256 + (seg == 2 ? 128 : 0) +
                            khalf + c * 8);
                    } else {
                        const unsigned short* Ap = (seg == 5) ? Alo : Ahi;
                        v = *reinterpret_cast<const short8v*>(
                            Ap + (size_t)node * 128 + khalf + c * 8);
                    }
                }
                fv[j] = v;
            }
            #pragma unroll
            for (int j = 0; j < 4; ++j)
                wv[j] = *reinterpret_cast<const short8v*>(
                    wseg[seg] + (size_t)(fr + j * 32) * 128 + khalf + c * 8);
        }

        // ---- compute tile t ----
        #pragma unroll
        for (int ks = 0; ks < 2; ++ks) {
            const int cc = ((ks * 4 + lk) ^ (lr & 7)) * 8;
            short8v a[2], b[4];
            #pragma unroll
            for (int mi = 0; mi < 2; ++mi) {
                const int row = wm * 32 + mi * 16 + lr;
                a[mi] = *reinterpret_cast<const short8v*>(&Fs[row * 64 + cc]);
            }
            #pragma unroll
            for (int ni = 0; ni < 4; ++ni) {
                const int o = wn * 64 + ni * 16 + lr;
                b[ni] = *reinterpret_cast<const short8v*>(&Ws[o * 64 + cc]);
            }
            #pragma unroll
            for (int mi = 0; mi < 2; ++mi)
                #pragma unroll
                for (int ni = 0; ni < 4; ++ni)
                    acc[mi][ni] = __builtin_amdgcn_mfma_f32_16x16x32_bf16(
                        a[mi], b[ni], acc[mi][ni], 0, 0, 0);
        }
    }

    // ---- epilogue: bias + relu; C/D layout col=lane&15, row=(lane>>4)*4+r ----
    #pragma unroll
    for (int ni = 0; ni < 4; ++ni) {
        const int o = wn * 64 + ni * 16 + lr;
        const float bo = bias[o];
        #pragma unroll
        for (int mi = 0; mi < 2; ++mi) {
            const int nodeb = node0 + wm * 32 + mi * 16 + lk * 4;
            #pragma unroll
            for (int r = 0; r < 4; ++r) {
                const int node = nodeb + r;
                if (node < n_nodes)
                    out[(size_t)node * OUT_DIM + o] =
                        fmaxf(acc[mi][ni][r] + bo, 0.f);
            }
        }
    }
}

// ===========================================================================
// f32 fallback GEMM (unchanged from R2)
// ===========================================================================
__global__ __launch_bounds__(256)
void gemm_kernel(const float* __restrict__ X,
                 const float* __restrict__ A,
                 const float* __restrict__ Wself,
                 const float* __restrict__ Wneigh,
                 const float* __restrict__ bias,
                 float* __restrict__ out,
                 int n_nodes) {
    __shared__ alignas(16) float Wt[KT][132];
    __shared__ alignas(16) float Xs[BM][KT + 4];

    const int tid   = threadIdx.x;
    const int o_grp = tid & 31;
    const int n_grp = tid >> 5;
    const int node0 = blockIdx.x * BM;

    float acc[8][4];
    #pragma unroll
    for (int i = 0; i < 8; ++i)
        #pragma unroll
        for (int j = 0; j < 4; ++j) acc[i][j] = 0.f;

    for (int kt = 0; kt < 2 * IN_DIM; kt += KT) {
        const float* Wsrc = (kt < IN_DIM) ? Wself : Wneigh;
        const float* Fsrc = (kt < IN_DIM) ? X : A;
        const int kbase = kt & (IN_DIM - 1);
        __syncthreads();
        {
            const int k4 = tid & 7;
            int o = tid >> 3;
            #pragma unroll
            for (int p = 0; p < 4; ++p, o += 32) {
                float4 w = *reinterpret_cast<const float4*>(
                    Wsrc + o * IN_DIM + kbase + k4 * 4);
                Wt[k4 * 4 + 0][o] = w.x;
                Wt[k4 * 4 + 1][o] = w.y;
                Wt[k4 * 4 + 2][o] = w.z;
                Wt[k4 * 4 + 3][o] = w.w;
            }
        }
        {
            const int k4 = tid & 7;
            int n = tid >> 3;
            #pragma unroll
            for (int p = 0; p < 2; ++p, n += 32) {
                const int node = node0 + n;
                float4 x = make_float4(0.f, 0.f, 0.f, 0.f);
                if (node < n_nodes)
                    x = *reinterpret_cast<const float4*>(
                        Fsrc + (size_t)node * IN_DIM + kbase + k4 * 4);
                *reinterpret_cast<float4*>(&Xs[n][k4 * 4]) = x;
            }
        }
        __syncthreads();
        #pragma unroll
        for (int k4 = 0; k4 < KT; k4 += 4) {
            float4 w0 = *reinterpret_cast<const float4*>(&Wt[k4 + 0][o_grp * 4]);
            float4 w1 = *reinterpret_cast<const float4*>(&Wt[k4 + 1][o_grp * 4]);
            float4 w2 = *reinterpret_cast<const float4*>(&Wt[k4 + 2][o_grp * 4]);
            float4 w3 = *reinterpret_cast<const float4*>(&Wt[k4 + 3][o_grp * 4]);
            #pragma unroll
            for (int nn = 0; nn < 8; ++nn) {
                float4 x = *reinterpret_cast<const float4*>(
                    &Xs[n_grp * 8 + nn][k4]);
                acc[nn][0] = fmaf(x.x, w0.x, acc[nn][0]);
                acc[nn][0] = fmaf(x.y, w1.x, acc[nn][0]);
                acc[nn][0] = fmaf(x.z, w2.x, acc[nn][0]);
                acc[nn][0] = fmaf(x.w, w3.x, acc[nn][0]);
                acc[nn][1] = fmaf(x.x, w0.y, acc[nn][1]);
                acc[nn][1] = fmaf(x.y, w1.y, acc[nn][1]);
                acc[nn][1] = fmaf(x.z, w2.y, acc[nn][1]);
                acc[nn][1] = fmaf(x.w, w3.y, acc[nn][1]);
                acc[nn][2] = fmaf(x.x, w0.z, acc[nn][2]);
                acc[nn][2] = fmaf(x.y, w1.z, acc[nn][2]);
                acc[nn][2] = fmaf(x.z, w2.z, acc[nn][2]);
                acc[nn][2] = fmaf(x.w, w3.z, acc[nn][2]);
                acc[nn][3] = fmaf(x.x, w0.w, acc[nn][3]);
                acc[nn][3] = fmaf(x.y, w1.w, acc[nn][3]);
                acc[nn][3] = fmaf(x.z, w2.w, acc[nn][3]);
                acc[nn][3] = fmaf(x.w, w3.w, acc[nn][3]);
            }
        }
    }

    const float4 b = *reinterpret_cast<const float4*>(bias + o_grp * 4);
    #pragma unroll
    for (int nn = 0; nn < 8; ++nn) {
        const int node = node0 + n_grp * 8 + nn;
        if (node < n_nodes) {
            float4 r;
            r.x = fmaxf(acc[nn][0] + b.x, 0.f);
            r.y = fmaxf(acc[nn][1] + b.y, 0.f);
            r.z = fmaxf(acc[nn][2] + b.z, 0.f);
            r.w = fmaxf(acc[nn][3] + b.w, 0.f);
            *reinterpret_cast<float4*>(
                out + (size_t)node * OUT_DIM + o_grp * 4) = r;
        }
    }
}

// ===========================================================================
extern "C" void kernel_launch(void* const* d_in, const int* in_sizes, int n_in,
                              void* d_out, int out_size, void* d_ws, size_t ws_size,
                              hipStream_t stream) {
    const float* X      = (const float*)d_in[0];
    const int*   src    = (const int*)d_in[1];
    const int*   dst    = (const int*)d_in[2];
    const float* Wself  = (const float*)d_in[3];
    const float* Wneigh = (const float*)d_in[4];
    const float* bias   = (const float*)d_in[5];
    float*       out    = (float*)d_out;

    const int n_nodes = in_sizes[0] / IN_DIM;
    const int n_edges = in_sizes[1];
    const int nb = (n_nodes + 255) / 256;

    char* w = (char*)d_ws;
    auto take = [&](size_t bytes) {
        char* p = w;
        w += (bytes + 15) & ~(size_t)15;
        return p;
    };
    unsigned short* Ahi = (unsigned short*)take((size_t)n_nodes * IN_DIM * 2);
    unsigned short* Alo = (unsigned short*)take((size_t)n_nodes * IN_DIM * 2);
    int* counts    = (int*)take((size_t)n_nodes * sizeof(int));
    int* offs      = (int*)take((size_t)n_nodes * sizeof(int));
    int* cursor    = (int*)take((size_t)n_nodes * sizeof(int));
    int* bsums     = (int*)take((size_t)nb * sizeof(int));
    int* srcsorted = (int*)take((size_t)n_edges * sizeof(int));
    unsigned short* W1h = (unsigned short*)take((size_t)OUT_DIM * IN_DIM * 2);
    unsigned short* W1l = (unsigned short*)take((size_t)OUT_DIM * IN_DIM * 2);
    unsigned short* W2h = (unsigned short*)take((size_t)OUT_DIM * IN_DIM * 2);
    unsigned short* W2l = (unsigned short*)take((size_t)OUT_DIM * IN_DIM * 2);
    const size_t needed = (size_t)(w - (char*)d_ws);

    const int eblocks = (n_edges + 255) / 256;

    if (needed <= ws_size) {
        // ---- CSR binning + bf16x2-split MFMA path ----
        hipMemsetAsync(counts, 0, (size_t)n_nodes * sizeof(int), stream);
        hist_kernel<<<(n_edges / 4 + 256) / 256 + 1, 256, 0, stream>>>(dst, counts, n_edges);
        scan1_kernel<<<nb, 256, 0, stream>>>(counts, offs, bsums, n_nodes);
        scan2_kernel<<<1, 256, 0, stream>>>(bsums, nb);
        scan3_kernel<<<nb, 256, 0, stream>>>(offs, bsums, cursor, n_nodes);
        bucket_kernel<<<eblocks, 256, 0, stream>>>(src, dst, cursor, srcsorted,
                                                   n_edges);
        unsigned short* Xsp = (unsigned short*)d_out;   // X hi/lo packed in out slots
        xsplit_kernel<<<(n_nodes * 32 + 255) / 256, 256, 0, stream>>>(X, Xsp, n_nodes);
        wsplit_kernel<<<(OUT_DIM * IN_DIM + 255) / 256, 256, 0, stream>>>(
            Wself, Wneigh, W1h, W1l, W2h, W2l);
        accum_split_kernel<<<(n_nodes + 7) / 8, 256, 0, stream>>>(
            X, offs, srcsorted, Ahi, Alo, n_nodes, n_edges);
        mfma_gemm_kernel<<<(n_nodes + 63) / 64, 256, 0, stream>>>(
            Xsp, Ahi, Alo, W1h, W1l, W2h, W2l, bias, out, n_nodes);
    } else {
        // ---- fallback: f32 atomic scatter + f32 vector GEMM ----
        float* A = (float*)d_ws;
        hipMemsetAsync(A, 0, (size_t)n_nodes * IN_DIM * sizeof(float), stream);
        const long long sthreads = (long long)n_edges * 32;
        const int sblocks = (int)((sthreads + 255) / 256);
        scatter_kernel<<<sblocks, 256, 0, stream>>>(X, src, dst, A, n_edges);
        gemm_kernel<<<(n_nodes + BM - 1) / BM, 256, 0, stream>>>(
            X, A, Wself, Wneigh, bias, out, n_nodes);
    }
}